// Round 4
// baseline (1129.881 us; speedup 1.0000x reference)
//
#include <hip/hip_runtime.h>
#include <math.h>

#define BB 64
#define SS 4096
// ws layout (float offsets)
#define OF_G    0              // 2*4*256*20 = 40960 floats
#define OF_BG   40960          // 80
#define OF_DIST 41056          // 64*40 = 2560
#define OF_HFIN 43616          // 64*20 = 1280
#define OF_X    45056          // 64*4096*80 = 20971520
#define WS_NEEDED_FLOATS (OF_X + (size_t)BB * SS * 80)

#define L2E 1.4426950408889634f

typedef float v2f __attribute__((ext_vector_type(2)));

__device__ __forceinline__ float fast_rcp(float x) { return __builtin_amdgcn_rcpf(x); }
__device__ __forceinline__ float fast_exp2(float x) { return __builtin_amdgcn_exp2f(x); }
__device__ __forceinline__ float sigm_prec(float x) { return 1.0f / (1.0f + __expf(-x)); }

// ---------------- K0: G tables + combined bias + zero dist accumulator ----------
__global__ __launch_bounds__(256) void k_init(const float* __restrict__ pc_emb,
    const float* __restrict__ addr_emb, const float* __restrict__ enc_W,
    const float* __restrict__ b_ih, const float* __restrict__ b_hh,
    float* __restrict__ ws) {
  int gid = blockIdx.x * 256 + threadIdx.x;
  if (gid < 2048) {
    int t = gid >> 10;          // stream: 0=pc, 1=addr
    int i = (gid >> 8) & 3;     // byte position
    int byt = gid & 255;
    const float* tab = (t == 0 ? pc_emb : addr_emb) + (i * 256 + byt) * 20;
    float tv[20];
#pragma unroll
    for (int m = 0; m < 20; m++) tv[m] = tab[m];
    float* Grow = ws + OF_G + gid * 20;
#pragma unroll
    for (int j = 0; j < 20; j++) {
      float acc = 0.f;
#pragma unroll
      for (int m = 0; m < 20; m++) acc = fmaf(enc_W[j * 80 + i * 20 + m], tv[m], acc);
      Grow[j] = acc;
    }
  } else if (gid < 2048 + 80) {
    int g = gid - 2048;
    ws[OF_BG + g] = b_ih[g] + b_hh[g];
  } else if (gid < 2048 + 80 + 2560) {
    ws[OF_DIST + (gid - 2128)] = 0.f;
  }
}

// ---------------- K1: embed + encoder + X precompute (coalesced) + dist ---------
// X gate pre-activations are PRE-SCALED: i,f,o by -log2e; g by +2*log2e, so the
// LSTM activations need no multiply before exp2.
__global__ __launch_bounds__(64) void k_embed(const int* __restrict__ inp,
    const float* __restrict__ enc_b, const float* __restrict__ W_ih,
    float* __restrict__ ws) {
  __shared__ float lds[80 * 65];   // X-tile staged (padded); reused for e-transpose
  int b = blockIdx.x >> 6;
  int schunk = (blockIdx.x & 63) << 6;
  int t = threadIdx.x;
  int s = schunk + t;
  unsigned v0 = (unsigned)inp[(b * SS + s) * 2 + 0];
  unsigned v1 = (unsigned)inp[(b * SS + s) * 2 + 1];
  const float* G = ws + OF_G;
  float e[40];
#pragma unroll
  for (int st = 0; st < 2; st++) {
    unsigned v = (st == 0) ? v0 : v1;
    int by0 = (int)(v >> 24);
    int by1 = (int)((v >> 16) & 255u);
    int by2 = (int)((v >> 8) & 255u);
    int by3 = (int)(v & 255u);
    const float* G0 = G + ((st * 4 + 0) * 256 + by0) * 20;
    const float* G1 = G + ((st * 4 + 1) * 256 + by1) * 20;
    const float* G2 = G + ((st * 4 + 2) * 256 + by2) * 20;
    const float* G3 = G + ((st * 4 + 3) * 256 + by3) * 20;
#pragma unroll
    for (int j = 0; j < 20; j++) {
      float y = enc_b[j] + G0[j] + G1[j] + G2[j] + G3[j];
      e[st * 20 + j] = sigm_prec(y);
    }
  }
  // gates: W_ih rows are wave-uniform -> scalar loads; e in VGPRs; stage to LDS
  const float* bg = ws + OF_BG;
#pragma unroll 4
  for (int g = 0; g < 80; g++) {
    float a = bg[g];
#pragma unroll
    for (int d = 0; d < 40; d++) a = fmaf(W_ih[g * 40 + d], e[d], a);
    lds[g * 65 + t] = a;          // banks (g+t)%32: conflict-free
  }
  __syncthreads();
  // coalesced flush: float4 per (token, j), pre-scaled for exp2-based gates
  float4* XF4 = (float4*)(ws + OF_X) + (size_t)(b * SS + schunk) * 20;
#pragma unroll
  for (int it = 0; it < 20; it++) {
    int q = it * 64 + t;          // 0..1279
    int tok = q / 20;
    int jf = q - tok * 20;
    float4 vv;
    vv.x = lds[(0  + jf) * 65 + tok] * (-L2E);        // i
    vv.y = lds[(20 + jf) * 65 + tok] * (-L2E);        // f
    vv.z = lds[(40 + jf) * 65 + tok] * (2.0f * L2E);  // g
    vv.w = lds[(60 + jf) * 65 + tok] * (-L2E);        // o
    XF4[q] = vv;
  }
  __syncthreads();
  // dist partial sums: transpose e to LDS, 40 lanes column-sum, 1 atomic each
  float* eT = lds;                // 40*66 = 2640 <= 5200
#pragma unroll
  for (int d = 0; d < 40; d++) eT[d * 66 + t] = e[d];
  __syncthreads();
  if (t < 40) {
    float ssum = 0.f;
#pragma unroll 8
    for (int tok = 0; tok < 64; tok++) ssum += eT[t * 66 + tok];
    atomicAdd(ws + OF_DIST + b * 40 + t, ssum);
  }
}

// ---------------- K2: sequential LSTM, one wave per batch item ------------------
// Critical-path minimized: (1) all 20 h-broadcast readlanes hoisted ahead of the
// FMA chains (independent, pipeline back-to-back; only first use pays the
// SGPR-write hazard); (2) 4-way split accumulators cut the dependent FMA chain
// from 20 to 5 + 2 packed adds; (3) exp2-based activations with pre-scaled X.
__global__ __launch_bounds__(64) void k_lstm(const float* __restrict__ h0,
    const float* __restrict__ c0, const float* __restrict__ W_hh,
    float* __restrict__ ws) {
  int b = blockIdx.x;
  int l = threadIdx.x;
  int j = (l & 31) < 20 ? (l & 31) : 19;  // lanes >=20 mirror j=19 harmlessly
  v2f wif[20], wgo[20];
#pragma unroll
  for (int m = 0; m < 20; m++) {
    wif[m] = (v2f){W_hh[(0 * 20 + j) * 20 + m] * (-L2E),
                   W_hh[(1 * 20 + j) * 20 + m] * (-L2E)};
    wgo[m] = (v2f){W_hh[(2 * 20 + j) * 20 + m] * (2.0f * L2E),
                   W_hh[(3 * 20 + j) * 20 + m] * (-L2E)};
  }
  float h = h0[b * 20 + j];
  float c = c0[b * 20 + j];
  const float4* Xp = (const float4*)(ws + OF_X) + (size_t)b * SS * 20 + j;
  float4 xb[8];
#pragma unroll
  for (int p = 0; p < 8; p++) xb[p] = Xp[(size_t)p * 20];
  for (int s = 0; s < SS; s += 8) {
#pragma unroll
    for (int u = 0; u < 8; u++) {
      float4 x4 = xb[u];
      int sn = s + u + 8; if (sn > SS - 1) sn = SS - 1;
      xb[u] = Xp[(size_t)sn * 20];
      // ---- hoisted broadcast: 20 independent readlanes, no FMA between ----
      float hm[20];
#pragma unroll
      for (int m = 0; m < 20; m++)
        hm[m] = __int_as_float(__builtin_amdgcn_readlane(__float_as_int(h), m));
      // ---- 4-way split dot: chains of 5, issue-interleaved ----
      v2f aif0 = (v2f){x4.x, x4.y};
      v2f ago0 = (v2f){x4.z, x4.w};
      v2f aif1 = (v2f){0.f, 0.f}, ago1 = (v2f){0.f, 0.f};
      v2f aif2 = (v2f){0.f, 0.f}, ago2 = (v2f){0.f, 0.f};
      v2f aif3 = (v2f){0.f, 0.f}, ago3 = (v2f){0.f, 0.f};
#pragma unroll
      for (int m = 0; m < 5; m++) {
        v2f h0v = (v2f){hm[m], hm[m]};
        v2f h1v = (v2f){hm[5 + m], hm[5 + m]};
        v2f h2v = (v2f){hm[10 + m], hm[10 + m]};
        v2f h3v = (v2f){hm[15 + m], hm[15 + m]};
        aif0 = __builtin_elementwise_fma(wif[m],      h0v, aif0);
        ago0 = __builtin_elementwise_fma(wgo[m],      h0v, ago0);
        aif1 = __builtin_elementwise_fma(wif[5 + m],  h1v, aif1);
        ago1 = __builtin_elementwise_fma(wgo[5 + m],  h1v, ago1);
        aif2 = __builtin_elementwise_fma(wif[10 + m], h2v, aif2);
        ago2 = __builtin_elementwise_fma(wgo[10 + m], h2v, ago2);
        aif3 = __builtin_elementwise_fma(wif[15 + m], h3v, aif3);
        ago3 = __builtin_elementwise_fma(wgo[15 + m], h3v, ago3);
      }
      v2f aif = (aif0 + aif1) + (aif2 + aif3);
      v2f ago = (ago0 + ago1) + (ago2 + ago3);
      // pre-scaled gates: sigmoid = rcp(1+exp2(y)); tanh = 1-2*rcp(1+exp2(y))
      float si = fast_rcp(1.0f + fast_exp2(aif.x));
      float sf = fast_rcp(1.0f + fast_exp2(aif.y));
      float tg = fmaf(-2.0f, fast_rcp(1.0f + fast_exp2(ago.x)), 1.0f);
      float so = fast_rcp(1.0f + fast_exp2(ago.y));
      c = fmaf(sf, c, si * tg);
      float tc = fmaf(-2.0f, fast_rcp(1.0f + fast_exp2(c * (2.0f * L2E))), 1.0f);
      h = so * tc;
    }
  }
  if (l < 20) ws[OF_HFIN + b * 20 + l] = h;
}

// ---------------- K3: decoder heads + softmax over batch axis -------------------
__global__ __launch_bounds__(256) void k_dec(const float* __restrict__ dec_W,
    const float* __restrict__ dec_b, float* __restrict__ out,
    const float* __restrict__ ws) {
  int wid = blockIdx.x * 4 + (threadIdx.x >> 6);  // (k,v) pair id, 0..1023
  int lane = threadIdx.x & 63;                    // = batch index b
  int k = wid >> 8;
  int v = wid & 255;
  const float* hp = ws + OF_HFIN + lane * 20;
  const float* wp = dec_W + (k * 256 + v) * 20;
  float l = dec_b[k * 256 + v];
#pragma unroll
  for (int jj = 0; jj < 20; jj++) l = fmaf(hp[jj], wp[jj], l);
  float x = l / 0.001f;
  float mx = x;
#pragma unroll
  for (int off = 32; off; off >>= 1) mx = fmaxf(mx, __shfl_xor(mx, off));
  float ex = __expf(x - mx);
  float sm = ex;
#pragma unroll
  for (int off = 32; off; off >>= 1) sm += __shfl_xor(sm, off);
  float p = ex / sm;
  int oidx = (k * 64 + lane) * 256 + v;
  out[oidx] = p;            // probs
  out[65536 + oidx] = l;    // logits
}

// ---------------- K4: byte_e = probs @ addr_emb, encoder, MLP head --------------
__global__ __launch_bounds__(128) void k_freq(const float* __restrict__ addr_emb,
    const float* __restrict__ enc_W, const float* __restrict__ enc_b,
    const float* __restrict__ d1_W, const float* __restrict__ d1_b,
    const float* __restrict__ d2_W, const float* __restrict__ d2_b,
    float* __restrict__ out, const float* __restrict__ ws) {
  __shared__ float be[80];
  __shared__ float fr[60];
  __shared__ float r1[10];
  int b = blockIdx.x;
  int t = threadIdx.x;
  if (t < 80) {
    int k = t / 20, e2 = t % 20;
    const float* pp = out + (k * 64 + b) * 256;        // probs[k,0,b,:]
    const float* ap = addr_emb + (k * 256) * 20 + e2;
    float acc = 0.f;
    for (int v = 0; v < 256; v++) acc = fmaf(pp[v], ap[v * 20], acc);
    be[t] = acc;   // byte_e[b][k][e2], flat k*20+e2
  }
  __syncthreads();
  if (t < 20) {
    float acc = enc_b[t];
#pragma unroll
    for (int d = 0; d < 80; d++) acc = fmaf(enc_W[t * 80 + d], be[d], acc);
    fr[t] = 1.0f / (1.0f + __expf(-acc));              // fe
  } else if (t < 60) {
    fr[t] = ws[OF_DIST + b * 40 + (t - 20)] * (1.0f / 4096.0f);  // dist_vector
  }
  __syncthreads();
  if (t < 10) {
    float acc = d1_b[t];
#pragma unroll
    for (int d = 0; d < 60; d++) acc = fmaf(d1_W[t * 60 + d], fr[d], acc);
    r1[t] = acc > 0.f ? acc : 0.f;
  }
  __syncthreads();
  if (t < 2) {
    float acc = d2_b[t];
#pragma unroll
    for (int r = 0; r < 10; r++) acc = fmaf(d2_W[t * 10 + r], r1[r], acc);
    out[131072 + t * 64 + b] = acc;
  }
}

extern "C" void kernel_launch(void* const* d_in, const int* in_sizes, int n_in,
                              void* d_out, int out_size, void* d_ws, size_t ws_size,
                              hipStream_t stream) {
  const int*   inp    = (const int*)  d_in[0];
  const float* h0     = (const float*)d_in[1];
  const float* c0     = (const float*)d_in[2];
  const float* pc_emb = (const float*)d_in[3];
  const float* addr_e = (const float*)d_in[4];
  const float* enc_W  = (const float*)d_in[5];
  const float* enc_b  = (const float*)d_in[6];
  const float* W_ih   = (const float*)d_in[7];
  const float* W_hh   = (const float*)d_in[8];
  const float* b_ih   = (const float*)d_in[9];
  const float* b_hh   = (const float*)d_in[10];
  const float* dec_W  = (const float*)d_in[11];
  const float* dec_b  = (const float*)d_in[12];
  const float* d1_W   = (const float*)d_in[13];
  const float* d1_b   = (const float*)d_in[14];
  const float* d2_W   = (const float*)d_in[15];
  const float* d2_b   = (const float*)d_in[16];
  float* out = (float*)d_out;
  float* ws  = (float*)d_ws;

  if (ws_size < WS_NEEDED_FLOATS * sizeof(float)) return;

  hipLaunchKernelGGL(k_init, dim3(19), dim3(256), 0, stream,
                     pc_emb, addr_e, enc_W, b_ih, b_hh, ws);
  hipLaunchKernelGGL(k_embed, dim3(4096), dim3(64), 0, stream, inp, enc_b, W_ih, ws);
  hipLaunchKernelGGL(k_lstm, dim3(64), dim3(64), 0, stream, h0, c0, W_hh, ws);
  hipLaunchKernelGGL(k_dec, dim3(256), dim3(256), 0, stream, dec_W, dec_b, out, ws);
  hipLaunchKernelGGL(k_freq, dim3(64), dim3(128), 0, stream,
                     addr_e, enc_W, enc_b, d1_W, d1_b, d2_W, d2_b, out, ws);
}

// Round 5
// 1001.270 us; speedup vs baseline: 1.1284x; 1.1284x over previous
//
#include <hip/hip_runtime.h>
#include <math.h>

#define BB 64
#define SS 4096
// ws layout (float offsets)
#define OF_G    0              // 2*4*256*20 = 40960 floats
#define OF_BG   40960          // 80
#define OF_DIST 41056          // 64*40 = 2560
#define OF_HFIN 43616          // 64*20 = 1280
#define OF_X    45056          // 64*4096*80 floats + 8-step pad for clamp-free prefetch
#define WS_NEEDED_FLOATS (OF_X + (size_t)BB * SS * 80 + 8 * 80)

#define L2E 1.4426950408889634f

typedef float v2f __attribute__((ext_vector_type(2)));

__device__ __forceinline__ float fast_rcp(float x) { return __builtin_amdgcn_rcpf(x); }
__device__ __forceinline__ float fast_exp2(float x) { return __builtin_amdgcn_exp2f(x); }
__device__ __forceinline__ float sigm_prec(float x) { return 1.0f / (1.0f + __expf(-x)); }
#define RL(v, m) __int_as_float(__builtin_amdgcn_readlane(__float_as_int(v), (m)))

// ---------------- K0: G tables + combined bias + zero dist accumulator ----------
__global__ __launch_bounds__(256) void k_init(const float* __restrict__ pc_emb,
    const float* __restrict__ addr_emb, const float* __restrict__ enc_W,
    const float* __restrict__ b_ih, const float* __restrict__ b_hh,
    float* __restrict__ ws) {
  int gid = blockIdx.x * 256 + threadIdx.x;
  if (gid < 2048) {
    int t = gid >> 10;          // stream: 0=pc, 1=addr
    int i = (gid >> 8) & 3;     // byte position
    int byt = gid & 255;
    const float* tab = (t == 0 ? pc_emb : addr_emb) + (i * 256 + byt) * 20;
    float tv[20];
#pragma unroll
    for (int m = 0; m < 20; m++) tv[m] = tab[m];
    float* Grow = ws + OF_G + gid * 20;
#pragma unroll
    for (int j = 0; j < 20; j++) {
      float acc = 0.f;
#pragma unroll
      for (int m = 0; m < 20; m++) acc = fmaf(enc_W[j * 80 + i * 20 + m], tv[m], acc);
      Grow[j] = acc;
    }
  } else if (gid < 2048 + 80) {
    int g = gid - 2048;
    ws[OF_BG + g] = b_ih[g] + b_hh[g];
  } else if (gid < 2048 + 80 + 2560) {
    ws[OF_DIST + (gid - 2128)] = 0.f;
  }
}

// ---------------- K1: embed + encoder + X precompute (coalesced) + dist ---------
// X gate pre-activations are PRE-SCALED: i,f,o by -log2e; g by +2*log2e, so the
// LSTM activations need no multiply before exp2.
__global__ __launch_bounds__(64) void k_embed(const int* __restrict__ inp,
    const float* __restrict__ enc_b, const float* __restrict__ W_ih,
    float* __restrict__ ws) {
  __shared__ float lds[80 * 65];   // X-tile staged (padded); reused for e-transpose
  int b = blockIdx.x >> 6;
  int schunk = (blockIdx.x & 63) << 6;
  int t = threadIdx.x;
  int s = schunk + t;
  unsigned v0 = (unsigned)inp[(b * SS + s) * 2 + 0];
  unsigned v1 = (unsigned)inp[(b * SS + s) * 2 + 1];
  const float* G = ws + OF_G;
  float e[40];
#pragma unroll
  for (int st = 0; st < 2; st++) {
    unsigned v = (st == 0) ? v0 : v1;
    int by0 = (int)(v >> 24);
    int by1 = (int)((v >> 16) & 255u);
    int by2 = (int)((v >> 8) & 255u);
    int by3 = (int)(v & 255u);
    const float* G0 = G + ((st * 4 + 0) * 256 + by0) * 20;
    const float* G1 = G + ((st * 4 + 1) * 256 + by1) * 20;
    const float* G2 = G + ((st * 4 + 2) * 256 + by2) * 20;
    const float* G3 = G + ((st * 4 + 3) * 256 + by3) * 20;
#pragma unroll
    for (int j = 0; j < 20; j++) {
      float y = enc_b[j] + G0[j] + G1[j] + G2[j] + G3[j];
      e[st * 20 + j] = sigm_prec(y);
    }
  }
  // gates: W_ih rows are wave-uniform -> scalar loads; e in VGPRs; stage to LDS
  const float* bg = ws + OF_BG;
#pragma unroll 4
  for (int g = 0; g < 80; g++) {
    float a = bg[g];
#pragma unroll
    for (int d = 0; d < 40; d++) a = fmaf(W_ih[g * 40 + d], e[d], a);
    lds[g * 65 + t] = a;          // banks (g+t)%32: conflict-free
  }
  __syncthreads();
  // coalesced flush: float4 per (token, j), pre-scaled for exp2-based gates
  float4* XF4 = (float4*)(ws + OF_X) + (size_t)(b * SS + schunk) * 20;
#pragma unroll
  for (int it = 0; it < 20; it++) {
    int q = it * 64 + t;          // 0..1279
    int tok = q / 20;
    int jf = q - tok * 20;
    float4 vv;
    vv.x = lds[(0  + jf) * 65 + tok] * (-L2E);        // i
    vv.y = lds[(20 + jf) * 65 + tok] * (-L2E);        // f
    vv.z = lds[(40 + jf) * 65 + tok] * (2.0f * L2E);  // g
    vv.w = lds[(60 + jf) * 65 + tok] * (-L2E);        // o
    XF4[q] = vv;
  }
  __syncthreads();
  // dist partial sums: transpose e to LDS, 40 lanes column-sum, 1 atomic each
  float* eT = lds;                // 40*66 = 2640 <= 5200
#pragma unroll
  for (int d = 0; d < 40; d++) eT[d * 66 + t] = e[d];
  __syncthreads();
  if (t < 40) {
    float ssum = 0.f;
#pragma unroll 8
    for (int tok = 0; tok < 64; tok++) ssum += eT[t * 66 + tok];
    atomicAdd(ws + OF_DIST + b * 40 + t, ssum);
  }
}

// ---------------- K2: sequential LSTM, one wave per batch item ------------------
// Serial-trans-bound. Path: readlane bcast -> depth-10 pk_fma chains ->
// exp2 -> rcp -> c-fma -> exp2 -> rcp -> h. Cell state kept pre-scaled by
// 2*log2e so exp2(cs) needs no on-path mul. Clamp-free prefetch via X pad.
__global__ __launch_bounds__(64) void k_lstm(const float* __restrict__ h0,
    const float* __restrict__ c0, const float* __restrict__ W_hh,
    float* __restrict__ ws) {
  int b = blockIdx.x;
  int l = threadIdx.x;
  int j = (l & 31) < 20 ? (l & 31) : 19;  // lanes >=20 mirror j=19 harmlessly
  v2f wif[20], wgo[20];
#pragma unroll
  for (int m = 0; m < 20; m++) {
    wif[m] = (v2f){W_hh[(0 * 20 + j) * 20 + m] * (-L2E),
                   W_hh[(1 * 20 + j) * 20 + m] * (-L2E)};
    wgo[m] = (v2f){W_hh[(2 * 20 + j) * 20 + m] * (2.0f * L2E),
                   W_hh[(3 * 20 + j) * 20 + m] * (-L2E)};
  }
  float h = h0[b * 20 + j];
  float cs = c0[b * 20 + j] * (2.0f * L2E);   // pre-scaled cell state
  const float4* Xp = (const float4*)(ws + OF_X) + (size_t)b * SS * 20 + j;
  float4 xb[8];
#pragma unroll
  for (int p = 0; p < 8; p++) xb[p] = Xp[p * 20];
  const float4* Xq = Xp;
  for (int s = 0; s < SS; s += 8) {
#pragma unroll
    for (int u = 0; u < 8; u++) {
      float4 x4 = xb[u];
      xb[u] = Xq[(u + 8) * 20];   // constant-offset prefetch, 8 steps ahead
      float hm[20];
#pragma unroll
      for (int m = 0; m < 4; m++) hm[m] = RL(h, m);
      v2f aifA = (v2f){x4.x, x4.y};
      v2f agoA = (v2f){x4.z, x4.w};
      v2f aifB = (v2f){0.f, 0.f};
      v2f agoB = (v2f){0.f, 0.f};
      // two depth-10 chains, readlanes pipelined 4 ahead
#pragma unroll
      for (int m = 0; m < 10; m++) {
        hm[m + 4] = RL(h, m + 4);                // fills 4..13
        v2f hv = (v2f){hm[m], hm[m]};
        aifA = __builtin_elementwise_fma(wif[m], hv, aifA);
        agoA = __builtin_elementwise_fma(wgo[m], hv, agoA);
      }
#pragma unroll
      for (int m = 10; m < 20; m++) {
        if (m + 4 < 20) hm[m + 4] = RL(h, m + 4);  // fills 14..19
        v2f hv = (v2f){hm[m], hm[m]};
        aifB = __builtin_elementwise_fma(wif[m], hv, aifB);
        agoB = __builtin_elementwise_fma(wgo[m], hv, agoB);
      }
      v2f aif = aifA + aifB;
      v2f ago = agoA + agoB;
      float si = fast_rcp(1.0f + fast_exp2(aif.x));
      float sf = fast_rcp(1.0f + fast_exp2(aif.y));
      float tg = fmaf(-2.0f, fast_rcp(1.0f + fast_exp2(ago.x)), 1.0f);
      float so = fast_rcp(1.0f + fast_exp2(ago.y));
      float p2 = (si * tg) * (2.0f * L2E);       // off-path compensation mul
      cs = fmaf(sf, cs, p2);
      float tc = fmaf(-2.0f, fast_rcp(1.0f + fast_exp2(cs)), 1.0f);
      h = so * tc;
    }
    Xq += 8 * 20;
  }
  if (l < 20) ws[OF_HFIN + b * 20 + l] = h;
}

// ---------------- K3: decoder heads + softmax over batch axis -------------------
__global__ __launch_bounds__(256) void k_dec(const float* __restrict__ dec_W,
    const float* __restrict__ dec_b, float* __restrict__ out,
    const float* __restrict__ ws) {
  int wid = blockIdx.x * 4 + (threadIdx.x >> 6);  // (k,v) pair id, 0..1023
  int lane = threadIdx.x & 63;                    // = batch index b
  int k = wid >> 8;
  int v = wid & 255;
  const float* hp = ws + OF_HFIN + lane * 20;
  const float* wp = dec_W + (k * 256 + v) * 20;
  float l = dec_b[k * 256 + v];
#pragma unroll
  for (int jj = 0; jj < 20; jj++) l = fmaf(hp[jj], wp[jj], l);
  float x = l / 0.001f;
  float mx = x;
#pragma unroll
  for (int off = 32; off; off >>= 1) mx = fmaxf(mx, __shfl_xor(mx, off));
  float ex = __expf(x - mx);
  float sm = ex;
#pragma unroll
  for (int off = 32; off; off >>= 1) sm += __shfl_xor(sm, off);
  float p = ex / sm;
  int oidx = (k * 64 + lane) * 256 + v;
  out[oidx] = p;            // probs
  out[65536 + oidx] = l;    // logits
}

// ---------------- K4: byte_e = probs @ addr_emb, encoder, MLP head --------------
__global__ __launch_bounds__(128) void k_freq(const float* __restrict__ addr_emb,
    const float* __restrict__ enc_W, const float* __restrict__ enc_b,
    const float* __restrict__ d1_W, const float* __restrict__ d1_b,
    const float* __restrict__ d2_W, const float* __restrict__ d2_b,
    float* __restrict__ out, const float* __restrict__ ws) {
  __shared__ float be[80];
  __shared__ float fr[60];
  __shared__ float r1[10];
  int b = blockIdx.x;
  int t = threadIdx.x;
  if (t < 80) {
    int k = t / 20, e2 = t % 20;
    const float* pp = out + (k * 64 + b) * 256;        // probs[k,0,b,:]
    const float* ap = addr_emb + (k * 256) * 20 + e2;
    float acc = 0.f;
    for (int v = 0; v < 256; v++) acc = fmaf(pp[v], ap[v * 20], acc);
    be[t] = acc;   // byte_e[b][k][e2], flat k*20+e2
  }
  __syncthreads();
  if (t < 20) {
    float acc = enc_b[t];
#pragma unroll
    for (int d = 0; d < 80; d++) acc = fmaf(enc_W[t * 80 + d], be[d], acc);
    fr[t] = 1.0f / (1.0f + __expf(-acc));              // fe
  } else if (t < 60) {
    fr[t] = ws[OF_DIST + b * 40 + (t - 20)] * (1.0f / 4096.0f);  // dist_vector
  }
  __syncthreads();
  if (t < 10) {
    float acc = d1_b[t];
#pragma unroll
    for (int d = 0; d < 60; d++) acc = fmaf(d1_W[t * 60 + d], fr[d], acc);
    r1[t] = acc > 0.f ? acc : 0.f;
  }
  __syncthreads();
  if (t < 2) {
    float acc = d2_b[t];
#pragma unroll
    for (int r = 0; r < 10; r++) acc = fmaf(d2_W[t * 10 + r], r1[r], acc);
    out[131072 + t * 64 + b] = acc;
  }
}

extern "C" void kernel_launch(void* const* d_in, const int* in_sizes, int n_in,
                              void* d_out, int out_size, void* d_ws, size_t ws_size,
                              hipStream_t stream) {
  const int*   inp    = (const int*)  d_in[0];
  const float* h0     = (const float*)d_in[1];
  const float* c0     = (const float*)d_in[2];
  const float* pc_emb = (const float*)d_in[3];
  const float* addr_e = (const float*)d_in[4];
  const float* enc_W  = (const float*)d_in[5];
  const float* enc_b  = (const float*)d_in[6];
  const float* W_ih   = (const float*)d_in[7];
  const float* W_hh   = (const float*)d_in[8];
  const float* b_ih   = (const float*)d_in[9];
  const float* b_hh   = (const float*)d_in[10];
  const float* dec_W  = (const float*)d_in[11];
  const float* dec_b  = (const float*)d_in[12];
  const float* d1_W   = (const float*)d_in[13];
  const float* d1_b   = (const float*)d_in[14];
  const float* d2_W   = (const float*)d_in[15];
  const float* d2_b   = (const float*)d_in[16];
  float* out = (float*)d_out;
  float* ws  = (float*)d_ws;

  if (ws_size < WS_NEEDED_FLOATS * sizeof(float)) return;

  hipLaunchKernelGGL(k_init, dim3(19), dim3(256), 0, stream,
                     pc_emb, addr_e, enc_W, b_ih, b_hh, ws);
  hipLaunchKernelGGL(k_embed, dim3(4096), dim3(64), 0, stream, inp, enc_b, W_ih, ws);
  hipLaunchKernelGGL(k_lstm, dim3(64), dim3(64), 0, stream, h0, c0, W_hh, ws);
  hipLaunchKernelGGL(k_dec, dim3(256), dim3(256), 0, stream, dec_W, dec_b, out, ws);
  hipLaunchKernelGGL(k_freq, dim3(64), dim3(128), 0, stream,
                     addr_e, enc_W, enc_b, d1_W, d1_b, d2_W, d2_b, out, ws);
}